// Round 8
// baseline (1675.873 us; speedup 1.0000x reference)
//
#include <hip/hip_runtime.h>
#include <hip/hip_bf16.h>
#include <cstdint>
#include <cstddef>

#define B_   32
#define L_   12
#define N_   883
#define DM_  64
#define E_SP 14128
#define E_TP 144
#define NT_  12
#define RBN  28256      // B*N
#define RBL  384        // B*L
#define LDM  768        // L*DM
#define NDM  56512      // N*DM

static inline int cdiv_h(int a, int b){ return (a+b-1)/b; }

// bf16 round-to-nearest-even from float
__device__ __forceinline__ ushort f2bf(float f){
    unsigned u = __float_as_uint(f);
    unsigned lsb = (u >> 16) & 1u;
    u += 0x7fffu + lsb;
    return (ushort)(u >> 16);
}
__device__ __forceinline__ float bf2f(ushort h){
    return __uint_as_float(((unsigned)h) << 16);
}

typedef __bf16 bf16x8 __attribute__((ext_vector_type(8)));
typedef float  f32x4  __attribute__((ext_vector_type(4)));
typedef short  s16x2  __attribute__((ext_vector_type(2)));
union BF8 { bf16x8 v; ushort u[8]; unsigned w[4]; int4 i; };

// packed relu on 2 bf16 (sign-magnitude => signed-i16 max-with-0 is exact relu)
__device__ __forceinline__ unsigned pkrelu(unsigned x){
    s16x2 v;
    __builtin_memcpy(&v, &x, 4);
    s16x2 z = 0;
    v = __builtin_elementwise_max(v, z);
    unsigned r;
    __builtin_memcpy(&r, &v, 4);
    return r;
}

// ============================ res: X = hist @ start_w + start_b (hi/lo bf16) ==============
__global__ void k_res(const float* __restrict__ hist, const float* __restrict__ sw,
                      const float* __restrict__ sb, ushort* __restrict__ resHi,
                      ushort* __restrict__ resLo)
{
    int idx = blockIdx.x*256 + threadIdx.x;
    if (idx >= RBN*LDM) return;
    int r = idx / LDM, col = idx - r*LDM;
    int b = r / N_, n = r - b*N_;
    int l = col >> 6, d = col & 63;
    const float* hp = hist + ((size_t)(b*L_ + l)*N_ + n)*3;
    float v = hp[0]*sw[d] + hp[1]*sw[64+d] + hp[2]*sw[128+d] + sb[d];
    ushort hi = f2bf(v);
    resHi[idx] = hi;
    resLo[idx] = f2bf(v - bf2f(hi));
}

// ============== generalized MFMA GEMM (direct-from-global) ==============
// A bf16. AMODE 0: A[r*K+k]. AMODE 1: r=(b*883+n), k=(l*64+d), addr (b*12+l)*56512 + n*64 + d.
// EPI 0: bf16 out[r*N+c]. EPI 1: f32 out[r*N+c]. EPI 2: head scatter f32 out[(b*12+c)*883+n], c<12.
// EPI 3: bf16 AT scatter out[(b*12+(c>>6))*56512 + n*64 + (c&63)].
// RES (EPI 0 only): v += resF[r*N+c], resF written back fp32.
template<int CT, int AMODE, int EPI, bool RELU, bool RES>
__launch_bounds__(256)
__global__ void mgemm(const ushort* __restrict__ A, const ushort* __restrict__ WT,
                      const float* __restrict__ bias, float* __restrict__ resF,
                      void* __restrict__ outP, int M, int N, int K)
{
    const int t = threadIdx.x, wv = t >> 6, l = t & 63;
    const int lr = l & 15, lk = l >> 4;
    const int row0 = blockIdx.y*64 + wv*16;
    const int col0 = blockIdx.x * (CT*16);
    int arr = row0 + lr; if (arr >= M) arr = M-1;
    int ab = 0, an = 0;
    if (AMODE == 1) { ab = arr / N_; an = arr - ab*N_; }
    const ushort* ap = A + (size_t)arr*K + lk*8;
    f32x4 acc[CT] = {};
    for (int k0 = 0; k0 < K; k0 += 32) {
        BF8 af;
        if (AMODE == 0) af.i = *(const int4*)(ap + k0);
        else {
            int k = k0 + lk*8; int ll = k >> 6, d = k & 63;
            af.i = *(const int4*)(A + ((size_t)(ab*L_ + ll))*NDM + (size_t)an*64 + d);
        }
        #pragma unroll
        for (int ct = 0; ct < CT; ++ct) {
            BF8 bf; bf.i = *(const int4*)&WT[(size_t)(col0 + ct*16 + lr)*K + k0 + lk*8];
            acc[ct] = __builtin_amdgcn_mfma_f32_16x16x32_bf16(af.v, bf.v, acc[ct], 0, 0, 0);
        }
    }
    #pragma unroll
    for (int ct = 0; ct < CT; ++ct) {
        int c = col0 + ct*16 + lr;
        float bv = 0.f;
        if (EPI == 2) { if (bias && c < 12) bv = bias[c]; }
        else if (bias) bv = bias[c];
        #pragma unroll
        for (int g = 0; g < 4; ++g) {
            int r = row0 + lk*4 + g;
            if (r >= M) continue;
            float v = acc[ct][g] + bv;
            if (RELU) v = fmaxf(v, 0.f);
            if (RES) {
                v += resF[(size_t)r*N + c];
                resF[(size_t)r*N + c] = v;
            }
            if (EPI == 0) {
                ((ushort*)outP)[(size_t)r*N + c] = f2bf(v);
            } else if (EPI == 1) {
                ((float*)outP)[(size_t)r*N + c] = v;
            } else if (EPI == 2) {
                if (c < 12) {
                    int b = r / N_, n = r - (r/N_)*N_;
                    ((float*)outP)[((size_t)(b*L_ + c))*N_ + n] = v;
                }
            } else {
                int b = r / N_, n = r - (r/N_)*N_;
                ((ushort*)outP)[((size_t)(b*L_ + (c>>6)))*NDM + (size_t)n*64 + (c&63)] = f2bf(v);
            }
        }
    }
}

// ============== hi/lo split MFMA GEMM (near-fp32 precision), fp32 out ==============
template<int CT>
__launch_bounds__(256)
__global__ void mgemm_hl(const ushort* __restrict__ Ahi, const ushort* __restrict__ Alo,
                         const ushort* __restrict__ WThi, const ushort* __restrict__ WTlo,
                         const float* __restrict__ bias, float* __restrict__ outF,
                         int M, int N, int K)
{
    const int t = threadIdx.x, wv = t >> 6, l = t & 63;
    const int lr = l & 15, lk = l >> 4;
    const int row0 = blockIdx.y*64 + wv*16;
    const int col0 = blockIdx.x * (CT*16);
    int arr = row0 + lr; if (arr >= M) arr = M-1;
    const ushort* aph = Ahi + (size_t)arr*K + lk*8;
    const ushort* apl = Alo + (size_t)arr*K + lk*8;
    f32x4 acc[CT] = {};
    for (int k0 = 0; k0 < K; k0 += 32) {
        BF8 ah, al_;
        ah.i  = *(const int4*)(aph + k0);
        al_.i = *(const int4*)(apl + k0);
        #pragma unroll
        for (int ct = 0; ct < CT; ++ct) {
            size_t wo = (size_t)(col0 + ct*16 + lr)*K + k0 + lk*8;
            BF8 bh, bl;
            bh.i = *(const int4*)&WThi[wo];
            bl.i = *(const int4*)&WTlo[wo];
            acc[ct] = __builtin_amdgcn_mfma_f32_16x16x32_bf16(ah.v,  bh.v, acc[ct], 0, 0, 0);
            acc[ct] = __builtin_amdgcn_mfma_f32_16x16x32_bf16(al_.v, bh.v, acc[ct], 0, 0, 0);
            acc[ct] = __builtin_amdgcn_mfma_f32_16x16x32_bf16(ah.v,  bl.v, acc[ct], 0, 0, 0);
        }
    }
    #pragma unroll
    for (int ct = 0; ct < CT; ++ct) {
        int c = col0 + ct*16 + lr;
        float bv = bias ? bias[c] : 0.f;
        #pragma unroll
        for (int g = 0; g < 4; ++g) {
            int r = row0 + lk*4 + g;
            if (r >= M) continue;
            outF[(size_t)r*N + c] = acc[ct][g] + bv;
        }
    }
}

// ============== temp_in via split-K MFMA: out[384][128] += AT @ WtT^T ==============
#define TCH 1024
__launch_bounds__(256)
__global__ void temp_in_mfma(const ushort* __restrict__ AT, const ushort* __restrict__ WtT,
                             float* __restrict__ out)
{
    const int t = threadIdx.x, wv = t >> 6, l = t & 63;
    const int lr = l & 15, lk = l >> 4;
    const int row0 = blockIdx.y * 96;
    const int c0 = wv * 32;
    const int k0b = blockIdx.x * TCH;
    const int kend = (k0b + TCH < NDM) ? (k0b + TCH) : NDM;
    f32x4 acc[6][2] = {};
    for (int k0 = k0b; k0 < kend; k0 += 32) {
        BF8 b0, b1;
        b0.i = *(const int4*)&WtT[(size_t)(c0 + lr)*NDM + k0 + lk*8];
        b1.i = *(const int4*)&WtT[(size_t)(c0 + 16 + lr)*NDM + k0 + lk*8];
        #pragma unroll
        for (int m = 0; m < 6; ++m) {
            BF8 af; af.i = *(const int4*)&AT[(size_t)(row0 + m*16 + lr)*NDM + k0 + lk*8];
            acc[m][0] = __builtin_amdgcn_mfma_f32_16x16x32_bf16(af.v, b0.v, acc[m][0], 0, 0, 0);
            acc[m][1] = __builtin_amdgcn_mfma_f32_16x16x32_bf16(af.v, b1.v, acc[m][1], 0, 0, 0);
        }
    }
    #pragma unroll
    for (int m = 0; m < 6; ++m)
        #pragma unroll
        for (int ct = 0; ct < 2; ++ct) {
            int c = c0 + ct*16 + lr;
            #pragma unroll
            for (int g = 0; g < 4; ++g) {
                int r = row0 + m*16 + lk*4 + g;
                atomicAdd(&out[(size_t)r*128 + c], acc[m][ct][g]);
            }
        }
}

// ============================ attention scores (bf16 h) ============================
__global__ void k_sc(const ushort* __restrict__ h, const float* __restrict__ as_,
                     const float* __restrict__ ad_, float* __restrict__ scs,
                     float* __restrict__ scd, int R)
{
    int r = blockIdx.x*256 + threadIdx.x;
    if (r >= R) return;
    const ushort* hr = h + (size_t)r*128;
    #pragma unroll
    for (int hh = 0; hh < 4; ++hh) {
        float ss = 0.f, sd = 0.f;
        #pragma unroll
        for (int k = 0; k < 32; ++k) {
            float hv = bf2f(hr[hh*32 + k]);
            ss += hv*as_[hh*32+k];
            sd += hv*ad_[hh*32+k];
        }
        scs[(size_t)r*4+hh] = ss;
        scd[(size_t)r*4+hh] = sd;
    }
}

// ================= edge softmax (no max-sub: logits are O(1), exp cannot overflow) ========
__global__ void k_attE(const float* __restrict__ scs, const float* __restrict__ scd,
                       const int* __restrict__ ei, int E, int NN,
                       float* __restrict__ a_buf, float* __restrict__ nsum)
{
    int idx = blockIdx.x*256 + threadIdx.x;
    if (idx >= B_*E) return;
    int b = idx / E, e = idx - b*E;
    int s = ei[e], tg = ei[E+e];
    const float* ps = scs + (size_t)(b*NN+s)*4;
    const float* pd = scd + (size_t)(b*NN+tg)*4;
    float* ns = nsum + (size_t)(b*NN+tg)*4;
    float* pa = a_buf + (size_t)idx*4;
    #pragma unroll
    for (int hh = 0; hh < 4; ++hh) {
        float al = ps[hh] + pd[hh];
        al = al > 0.f ? al : 0.2f*al;
        float ex = expf(al);
        pa[hh] = ex;
        atomicAdd(ns + hh, ex);
    }
}

// ============================ CSR build (target-indexed) ============================
__global__ void k_count(const int* __restrict__ ei, int E, int* __restrict__ counts){
    int e = blockIdx.x*256 + threadIdx.x;
    if (e < E) atomicAdd(&counts[ei[E + e]], 1);
}
__global__ void k_scan(const int* __restrict__ counts, int* __restrict__ off,
                       int* __restrict__ cur, int n)
{
    __shared__ int s[1024];
    int t = threadIdx.x;
    int v0 = (t < n) ? counts[t] : 0;
    s[t] = v0;
    __syncthreads();
    for (int o = 1; o < 1024; o <<= 1) {
        int v = (t >= o) ? s[t-o] : 0;
        __syncthreads();
        s[t] += v;
        __syncthreads();
    }
    if (t < n) {
        off[t+1] = s[t];
        cur[t] = s[t] - v0;
        if (t == 0) off[0] = 0;
    }
}
__global__ void k_fill(const int* __restrict__ ei, int E, int* __restrict__ cur,
                       int* __restrict__ lst){
    int e = blockIdx.x*256 + threadIdx.x;
    if (e < E) {
        int pos = atomicAdd(&cur[ei[E+e]], 1);
        lst[pos] = e;
    }
}

// ====================== GAT aggregation (4 waves/block, one wave per (b,n)) ==============
template<bool USE_ATT>
__global__ void k_gather(const ushort* __restrict__ h, const float* __restrict__ a_buf,
                         const float* __restrict__ nsum, const float* __restrict__ att,
                         const int* __restrict__ ei, const int* __restrict__ off,
                         const int* __restrict__ lst, const float* __restrict__ bias,
                         ushort* __restrict__ out, int E, int NN)
{
    int bn = blockIdx.x*4 + (threadIdx.x >> 6);
    int b = bn / NN, n = bn - b*NN;
    int lane = threadIdx.x & 63;
    int c0 = lane*2;
    int hh = lane >> 4;
    float rn = 1.f / nsum[(size_t)bn*4 + hh];
    int o0 = off[n], o1 = off[n+1];
    float ax = 0.f, ay = 0.f;
    for (int i = o0; i < o1; ++i) {
        int e = lst[i];
        float a = a_buf[((size_t)b*E + e)*4 + hh] * rn;
        if (USE_ATT) a *= att[(size_t)b*E + e];
        int s = ei[e];
        unsigned hv = *(const unsigned*)&h[((size_t)b*NN + s)*128 + c0];
        ax += a * __uint_as_float(hv << 16);
        ay += a * __uint_as_float(hv & 0xffff0000u);
    }
    ushort2 o2;
    o2.x = f2bf(ax + bias[c0]);
    o2.y = f2bf(ay + bias[c0+1]);
    *(ushort2*)&out[(size_t)bn*128 + c0] = o2;
}

// ============================ weight prep kernels ============================
__global__ void k_prepW2(const float* __restrict__ W2, ushort* __restrict__ W2T)
{
    int idx = blockIdx.x*256 + threadIdx.x;   // 512*128
    if (idx >= 512*128) return;
    int k = idx >> 7, c = idx & 127;
    W2T[(size_t)c*512 + k] = f2bf(W2[idx]);
}
// generic W[K][N] -> WT[N][K] bf16
__global__ void k_prepT(const float* __restrict__ W, ushort* __restrict__ WT, int K, int N)
{
    int idx = blockIdx.x*256 + threadIdx.x;
    if (idx >= K*N) return;
    int k = idx / N, c = idx - k*N;
    WT[(size_t)c*K + k] = f2bf(W[idx]);
}
// W[K][N] -> hi/lo transposed
__global__ void k_prepT_hl(const float* __restrict__ W, ushort* __restrict__ WThi,
                           ushort* __restrict__ WTlo, int K, int N)
{
    int idx = blockIdx.x*256 + threadIdx.x;
    if (idx >= K*N) return;
    int k = idx / N, c = idx - k*N;
    float v = W[idx];
    ushort hi = f2bf(v);
    WThi[(size_t)c*K + k] = hi;
    WTlo[(size_t)c*K + k] = f2bf(v - bf2f(hi));
}
// tr_temp_w [56512][128] -> WtT [128][56512] bf16 (tiled)
__global__ void k_prepWtT(const float* __restrict__ W, ushort* __restrict__ WT)
{
    __shared__ ushort tile[128][129];
    int k0 = blockIdx.x * 128;
    int t = threadIdx.x;
    for (int i = t; i < 128*128; i += 256) {
        int k = i >> 7, c = i & 127;
        int kk = k0 + k;
        tile[c][k] = (kk < NDM) ? f2bf(W[(size_t)kk*128 + c]) : (ushort)0;
    }
    __syncthreads();
    for (int i = t; i < 128*128; i += 256) {
        int c = i >> 7, k = i & 127;
        int kk = k0 + k;
        if (kk < NDM) WT[(size_t)c*NDM + kk] = tile[c][k];
    }
}
// inv_temp_w [128][56512] -> WT [56512][128] bf16 (tiled, 64 cols/block)
__global__ void k_prepT_big(const float* __restrict__ W, ushort* __restrict__ WT)
{
    __shared__ float tile[128][65];
    int c0 = blockIdx.x * 64;
    int t = threadIdx.x;
    for (int i = t; i < 128*64; i += 256) {
        int k = i >> 6, ci = i & 63;
        tile[k][ci] = W[(size_t)k*NDM + c0 + ci];
    }
    __syncthreads();
    for (int i = t; i < 64*128; i += 256) {
        int ci = i >> 7, k = i & 127;
        WT[(size_t)(c0 + ci)*128 + k] = f2bf(tile[k][ci]);
    }
}
// bias concat: [b1, zeros]
__global__ void k_bcat(const float* __restrict__ b1, float* __restrict__ dst){
    int i = blockIdx.x*256 + threadIdx.x;
    if (i < 1024) dst[i] = (i < 512) ? b1[i] : 0.f;
}

// ======== MFMA fused extractor stage2 — barrier-free, register-resident B ========
// att = sigmoid(relu(relu(P[es]+Q[et])@W2+b2)@w3+b3).
// PQ: bf16 [rows][1024] (P cols 0-511, Q cols 512-1023). W2T: bf16 [128 cols][512 k].
// 256 edge-rows/block, 4 waves, 4 row-tiles/wave, 8 col-tiles. NO LDS, NO __syncthreads:
// W2T is only 128 KB and L2/L1-hot (every wave reads the same lines each kc). B fragments
// live in regs with staggered reload (consume bf[ct] for kc, immediately reload for kc+1);
// A (P/Q gather regs) reloaded for kc+1 right after the kc repack. Every load thus has
// ~1 full iteration of slack — latency hidden without barrier lockstep.
template<bool SWZ>
__launch_bounds__(256, 2)
__global__ void ext2_mfma(const ushort* __restrict__ PQ, const ushort* __restrict__ W2T,
                          const float* __restrict__ b2, const float* __restrict__ w3,
                          const float* __restrict__ b3p, const int* __restrict__ ei,
                          float* __restrict__ att, int E, int NN, int nblk)
{
    int bid = blockIdx.x;
    if (SWZ) {
        bid = (blockIdx.x & 7) * (gridDim.x >> 3) + (blockIdx.x >> 3);
        if (bid >= nblk) bid = nblk - 1;
    }
    const int t = threadIdx.x;
    const int wv = t >> 6, l = t & 63;
    const int lr = l & 15, lk = l >> 4;

    const ushort* pr[4]; const ushort* qr[4];
    int row0[4];
    #pragma unroll
    for (int rt = 0; rt < 4; ++rt) {
        row0[rt] = bid*256 + wv*64 + rt*16;
        int r = row0[rt] + lr;
        int b = r / E, e = r - b*E;
        pr[rt] = PQ + ((size_t)b*NN + ei[e])*1024 + lk*8;
        qr[rt] = PQ + ((size_t)b*NN + ei[E+e])*1024 + 512 + lk*8;
    }
    // per-lane B base: col = ct*16 + lr, k = kc*32 + lk*8
    const ushort* wB = W2T + (size_t)lr*512 + lk*8;

    // prologue: A(0), B(0) -> regs
    BF8 pu[4], qu[4], bf[8];
    #pragma unroll
    for (int rt = 0; rt < 4; ++rt) {
        pu[rt].i = *(const int4*)(pr[rt]);
        qu[rt].i = *(const int4*)(qr[rt]);
    }
    #pragma unroll
    for (int ct = 0; ct < 8; ++ct)
        bf[ct].i = *(const int4*)(wB + (size_t)ct*16*512);

    f32x4 acc[4][8] = {};
    for (int kc = 0; kc < 16; ++kc) {
        // repack A(kc) from held regs
        BF8 af[4];
        #pragma unroll
        for (int rt = 0; rt < 4; ++rt)
            #pragma unroll
            for (int j = 0; j < 4; ++j) {
                unsigned up = pu[rt].w[j], uq = qu[rt].w[j];
                float rlo = __uint_as_float(up << 16)         + __uint_as_float(uq << 16);
                float rhi = __uint_as_float(up & 0xffff0000u) + __uint_as_float(uq & 0xffff0000u);
                unsigned pk = __builtin_amdgcn_perm(__float_as_uint(rhi), __float_as_uint(rlo),
                                                    0x07060302u);
                af[rt].w[j] = pkrelu(pk);
            }
        // reload A(kc+1) into the just-consumed regs (clamped tail)
        const int ka = (kc+1 < 15) ? kc+1 : 15;
        #pragma unroll
        for (int rt = 0; rt < 4; ++rt) {
            pu[rt].i = *(const int4*)(pr[rt] + ka*32);
            qu[rt].i = *(const int4*)(qr[rt] + ka*32);
        }
        // MFMA with staggered B reload: consume bf[ct] (kc), then reload it for kc+1
        #pragma unroll
        for (int ct = 0; ct < 8; ++ct) {
            BF8 cur = bf[ct];
            bf[ct].i = *(const int4*)(wB + (size_t)ct*16*512 + ka*32);
            #pragma unroll
            for (int rt = 0; rt < 4; ++rt)
                acc[rt][ct] = __builtin_amdgcn_mfma_f32_16x16x32_bf16(af[rt].v, cur.v,
                                                                     acc[rt][ct], 0, 0, 0);
        }
    }
    float b3 = b3p[0];
    #pragma unroll
    for (int rt = 0; rt < 4; ++rt) {
        float part[4] = {0.f,0.f,0.f,0.f};
        #pragma unroll
        for (int ct = 0; ct < 8; ++ct) {
            int c = ct*16 + lr;
            float b2v = b2[c], w3v = w3[c];
            #pragma unroll
            for (int g = 0; g < 4; ++g)
                part[g] += fmaxf(acc[rt][ct][g] + b2v, 0.f) * w3v;
        }
        #pragma unroll
        for (int m = 1; m < 16; m <<= 1)
            #pragma unroll
            for (int g = 0; g < 4; ++g)
                part[g] += __shfl_xor(part[g], m, 64);
        if (lr == 0) {
            #pragma unroll
            for (int g = 0; g < 4; ++g) {
                int rr = row0[rt] + lk*4 + g;
                att[rr] = 1.f/(1.f + expf(-(part[g] + b3)));
            }
        }
    }
}

// ============================ misc ============================
__global__ void k_bias_fill(float* __restrict__ dst, const float* __restrict__ bias, int n){
    int i = blockIdx.x*256 + threadIdx.x;
    if (i < n) dst[i] = bias[i & 127];
}
__global__ void k_f2b(const float* __restrict__ src, ushort* __restrict__ dst, int n){
    int i = blockIdx.x*256 + threadIdx.x;
    if (i < n) dst[i] = f2bf(src[i]);
}

// ============================ hid concat (fp32 + bf16 shadow) ============================
__global__ void k_hid(const float* __restrict__ ts_res, const float* __restrict__ ts_temp,
                      const float* __restrict__ node_emb, const float* __restrict__ tid_emb,
                      const float* __restrict__ diw_emb, const float* __restrict__ hist,
                      float* __restrict__ hid, ushort* __restrict__ hidB)
{
    int idx = blockIdx.x*256 + threadIdx.x;
    if (idx >= RBN*320) return;
    int r = idx / 320, c = idx - r*320;
    int b = r / N_, n = r - b*N_;
    float v;
    if (c < 64)        v = ts_res[(size_t)r*64 + c];
    else if (c < 128)  v = ts_temp[(size_t)r*64 + (c-64)];
    else if (c < 192)  v = node_emb[(size_t)n*64 + (c-128)];
    else if (c < 256) {
        int tid = (int)hist[((size_t)(b*L_ + (L_-1))*N_ + n)*3 + 1];
        v = tid_emb[(size_t)tid*64 + (c-192)];
    } else {
        int diw = (int)hist[((size_t)(b*L_ + (L_-1))*N_ + n)*3 + 2];
        v = diw_emb[(size_t)diw*64 + (c-256)];
    }
    hid[idx] = v;
    hidB[idx] = f2bf(v);
}

// =====================================================================================
extern "C" void kernel_launch(void* const* d_in, const int* in_sizes, int n_in,
                              void* d_out, int out_size, void* d_ws, size_t ws_size,
                              hipStream_t stream)
{
    (void)in_sizes; (void)n_in; (void)out_size; (void)ws_size;
    const float* hist      = (const float*)d_in[0];
    const int*   ei_sp     = (const int*)  d_in[1];
    const int*   ei_tp     = (const int*)  d_in[2];
    const float* node_emb  = (const float*)d_in[3];
    const float* tid_emb   = (const float*)d_in[4];
    const float* diw_emb   = (const float*)d_in[5];
    const float* start_w   = (const float*)d_in[6];
    const float* start_b   = (const float*)d_in[7];
    const float* ts_w      = (const float*)d_in[8];
    const float* ts_b      = (const float*)d_in[9];
    const float* tr_spat_w = (const float*)d_in[10];
    const float* tr_spat_b = (const float*)d_in[11];
    const float* inv_spat_w= (const float*)d_in[12];
    const float* inv_spat_b= (const float*)d_in[13];
    const float* tr_temp_w = (const float*)d_in[14];
    const float* tr_temp_b = (const float*)d_in[15];
    const float* inv_temp_w= (const float*)d_in[16];
    const float* inv_temp_b= (const float*)d_in[17];
    const float* gat_sp_w  = (const float*)d_in[18];
    const float* gat_sp_as = (const float*)d_in[19];
    const float* gat_sp_ad = (const float*)d_in[20];
    const float* gat_sp_b  = (const float*)d_in[21];
    const float* ext_sp_w1 = (const float*)d_in[22];
    const float* ext_sp_b1 = (const float*)d_in[23];
    const float* ext_sp_w2 = (const float*)d_in[24];
    const float* ext_sp_b2 = (const float*)d_in[25];
    const float* ext_sp_w3 = (const float*)d_in[26];
    const float* ext_sp_b3 = (const float*)d_in[27];
    const float* gat_tp_w  = (const float*)d_in[28];
    const float* gat_tp_as = (const float*)d_in[29];
    const float* gat_tp_ad = (const float*)d_in[30];
    const float* gat_tp_b  = (const float*)d_in[31];
    const float* ext_tp_w1 = (const float*)d_in[32];
    const float* ext_tp_b1 = (const float*)d_in[33];
    const float* ext_tp_w2 = (const float*)d_in[34];
    const float* ext_tp_b2 = (const float*)d_in[35];
    const float* ext_tp_w3 = (const float*)d_in[36];
    const float* ext_tp_b3 = (const float*)d_in[37];
    const float* enc_w1    = (const float*)d_in[38];
    const float* enc_b1    = (const float*)d_in[39];
    const float* enc_w2    = (const float*)d_in[40];
    const float* enc_b2    = (const float*)d_in[41];
    const float* reg_w     = (const float*)d_in[42];
    const float* reg_b     = (const float*)d_in[43];
    float* out = (float*)d_out;

    // ---------------- workspace layout (byte-granular, 256B aligned) ----------------
    size_t o = 0;
    char* wsb = (char*)d_ws;
    auto allocB = [&](size_t bytes) -> void* {
        void* p = wsb + o;
        o += (bytes + 255) & ~(size_t)255;
        return p;
    };
    // big reusable arenas
    void* bufA = allocB((size_t)RBN*768*2);   // resHi -> AT[384][56512]bf16 -> hid fp32[RBN][320]
    void* bufB = allocB((size_t)RBN*768*2);   // resLo -> PQ_sp[RBN][1024]bf16 (spills into bufC) -> tback
    void* bufC = allocB((size_t)RBN*512*2);   // (PQ_sp tail) -> hidB[RBN][320]bf16
    void* bufD = allocB((size_t)RBN*320*2);   // R1b (encoder temp bf16)
    float*  ts_res  = (float*)allocB((size_t)RBN*64*4);
    ushort* spaB    = (ushort*)allocB((size_t)RBN*128*2);  // spa_in -> spa_out
    ushort* hB      = (ushort*)allocB((size_t)RBN*128*2);  // h_sp -> h_tp
    float*  sc_s    = (float*)allocB((size_t)RBN*4*4);
    float*  sc_d    = (float*)allocB((size_t)RBN*4*4);
    float*  nsum    = (float*)allocB((size_t)RBN*4*4);
    float*  a_buf   = (float*)allocB((size_t)B_*E_SP*4*4);
    float*  att     = (float*)allocB((size_t)B_*E_SP*4);
    ushort* embB    = (ushort*)allocB((size_t)RBN*128*2);
    int*    csr     = (int*)allocB(17024*4);
    float*  temp_in = (float*)allocB((size_t)RBL*128*4);
    ushort* tempB   = (ushort*)allocB((size_t)RBL*128*2);
    ushort* toutB   = (ushort*)allocB((size_t)RBL*128*2);
    ushort* PQ_t    = (ushort*)allocB((size_t)RBL*1024*2);
    float*  ts_temp = (float*)allocB((size_t)RBN*64*4);
    // weight preps
    ushort* W2T_sp  = (ushort*)allocB(512*128*2);
    ushort* W2T_tp  = (ushort*)allocB(512*128*2);
    ushort* WtT     = (ushort*)allocB((size_t)128*NDM*2);   // tr_temp_w^T
    ushort* itWT    = (ushort*)allocB((size_t)NDM*128*2);   // inv_temp_w^T
    ushort* tspWT   = (ushort*)allocB(128*768*2);           // tr_spat_w^T
    ushort* ispWT   = (ushort*)allocB(768*128*2);           // inv_spat_w^T
    ushort* gspWT   = (ushort*)allocB(128*128*2);
    ushort* gtpWT   = (ushort*)allocB(128*128*2);
    ushort* w1catT_sp = (ushort*)allocB((size_t)1024*128*2);
    ushort* w1catT_tp = (ushort*)allocB((size_t)1024*128*2);
    float*  b1cat_sp  = (float*)allocB(1024*4);
    float*  b1cat_tp  = (float*)allocB(1024*4);
    ushort* w1T_enc = (ushort*)allocB((size_t)3*320*320*2);
    ushort* w2T_enc = (ushort*)allocB((size_t)3*320*320*2);
    ushort* tswT_hi = (ushort*)allocB(64*768*2);
    ushort* tswT_lo = (ushort*)allocB(64*768*2);
    ushort* reg_wT  = (ushort*)allocB(16*320*2);

    ushort* resHi = (ushort*)bufA;
    ushort* resLo = (ushort*)bufB;
    ushort* AT    = (ushort*)bufA;    // [384][56512]
    float*  hid   = (float*)bufA;     // [RBN][320] fp32
    ushort* PQ_sp = (ushort*)bufB;    // [RBN][1024] (57.9 MB, spans bufB+bufC)
    ushort* tback = (ushort*)bufB;    // [384][56512]
    ushort* hidB  = (ushort*)bufC;
    ushort* R1b   = (ushort*)bufD;

    int* counts_sp = csr;
    int* off_sp    = csr + 883;
    int* cur_sp    = csr + 1767;
    int* list_sp   = csr + 2650;
    int* counts_tp = csr + 16778;
    int* off_tp    = csr + 16790;
    int* cur_tp    = csr + 16803;
    int* list_tp   = csr + 16815;

    // ---------------- CSR builds + weight prep ----------------
    hipMemsetAsync(counts_sp, 0, 883*4, stream);
    k_count<<<cdiv_h(E_SP,256),256,0,stream>>>(ei_sp, E_SP, counts_sp);
    k_scan<<<1,1024,0,stream>>>(counts_sp, off_sp, cur_sp, 883);
    k_fill<<<cdiv_h(E_SP,256),256,0,stream>>>(ei_sp, E_SP, cur_sp, list_sp);
    hipMemsetAsync(counts_tp, 0, 12*4, stream);
    k_count<<<1,256,0,stream>>>(ei_tp, E_TP, counts_tp);
    k_scan<<<1,1024,0,stream>>>(counts_tp, off_tp, cur_tp, 12);
    k_fill<<<1,256,0,stream>>>(ei_tp, E_TP, cur_tp, list_tp);
    k_prepW2<<<cdiv_h(512*128,256),256,0,stream>>>(ext_sp_w2, W2T_sp);
    k_prepW2<<<cdiv_h(512*128,256),256,0,stream>>>(ext_tp_w2, W2T_tp);
    k_prepWtT<<<cdiv_h(NDM,128),256,0,stream>>>(tr_temp_w, WtT);
    k_prepT_big<<<NDM/64,256,0,stream>>>(inv_temp_w, itWT);
    k_prepT<<<cdiv_h(768*128,256),256,0,stream>>>(tr_spat_w, tspWT, 768, 128);
    k_prepT<<<cdiv_h(128*768,256),256,0,stream>>>(inv_spat_w, ispWT, 128, 768);
    k_prepT<<<cdiv_h(128*128,256),256,0,stream>>>(gat_sp_w, gspWT, 128, 128);
    k_prepT<<<cdiv_h(128*128,256),256,0,stream>>>(gat_tp_w, gtpWT, 128, 128);
    k_prepT<<<cdiv_h(128*512,256),256,0,stream>>>(ext_sp_w1,           w1catT_sp,           128, 512);
    k_prepT<<<cdiv_h(128*512,256),256,0,stream>>>(ext_sp_w1 + 128*512, w1catT_sp + 512*128, 128, 512);
    k_prepT<<<cdiv_h(128*512,256),256,0,stream>>>(ext_tp_w1,           w1catT_tp,           128, 512);
    k_prepT<<<cdiv_h(128*512,256),256,0,stream>>>(ext_tp_w1 + 128*512, w1catT_tp + 512*128, 128, 512);
    k_bcat<<<4,256,0,stream>>>(ext_sp_b1, b1cat_sp);
    k_bcat<<<4,256,0,stream>>>(ext_tp_b1, b1cat_tp);
    for (int i = 0; i < 3; ++i) {
        k_prepT<<<cdiv_h(320*320,256),256,0,stream>>>(enc_w1 + (size_t)i*320*320, w1T_enc + (size_t)i*320*320, 320, 320);
        k_prepT<<<cdiv_h(320*320,256),256,0,stream>>>(enc_w2 + (size_t)i*320*320, w2T_enc + (size_t)i*320*320, 320, 320);
    }
    k_prepT_hl<<<cdiv_h(768*64,256),256,0,stream>>>(ts_w, tswT_hi, tswT_lo, 768, 64);
    hipMemsetAsync(reg_wT, 0, 16*320*2, stream);
    k_prepT<<<cdiv_h(320*12,256),256,0,stream>>>(reg_w, reg_wT, 320, 12);

    // ---------------- res (hi/lo) / ts_res (hi-lo MFMA) / spa_in ----------------
    k_res<<<cdiv_h(RBN*LDM,256),256,0,stream>>>(hist, start_w, start_b, resHi, resLo);
    mgemm_hl<4><<<dim3(1,442),256,0,stream>>>(resHi, resLo, tswT_hi, tswT_lo, ts_b, ts_res,
                                              RBN, 64, LDM);
    mgemm<8,0,0,false,false><<<dim3(1,442),256,0,stream>>>(resHi, tspWT, tr_spat_b, nullptr,
                                                           spaB, RBN, 128, LDM);

    // ---------------- spatial GAT ----------------
    mgemm<8,0,0,false,false><<<dim3(1,442),256,0,stream>>>(spaB, gspWT, nullptr, nullptr,
                                                           hB, RBN, 128, 128);
    k_sc<<<cdiv_h(RBN,256),256,0,stream>>>(hB, gat_sp_as, gat_sp_ad, sc_s, sc_d, RBN);
    hipMemsetAsync(nsum, 0, (size_t)RBN*4*4, stream);
    k_attE<<<cdiv_h(B_*E_SP,256),256,0,stream>>>(sc_s, sc_d, ei_sp, E_SP, N_, a_buf, nsum);
    k_gather<false><<<RBN/4,256,0,stream>>>(hB, a_buf, nsum, nullptr, ei_sp, off_sp, list_sp,
                                            gat_sp_b, embB, E_SP, N_);
    // extractor: PQ = emb@[W1a|W1b] + [b1|0] (bf16); att = sigmoid(MLP) via MFMA
    mgemm<8,0,0,false,false><<<dim3(8,442),256,0,stream>>>(embB, w1catT_sp, b1cat_sp, nullptr,
                                                           PQ_sp, RBN, 1024, 128);
    ext2_mfma<true><<<1768,256,0,stream>>>(PQ_sp, W2T_sp, ext_sp_b2, ext_sp_w3, ext_sp_b3,
                                           ei_sp, att, E_SP, N_, (B_*E_SP)/256);
    k_gather<true><<<RBN/4,256,0,stream>>>(hB, a_buf, nsum, att, ei_sp, off_sp, list_sp,
                                           gat_sp_b, spaB, E_SP, N_);

    // ---------------- back-projection (bf16 AT) + temporal input (MFMA split-K) ----------
    mgemm<8,0,3,false,false><<<dim3(6,442),256,0,stream>>>(spaB, ispWT, inv_spat_b, nullptr,
                                                           AT, RBN, 768, 128);
    k_bias_fill<<<cdiv_h(RBL*128,256),256,0,stream>>>(temp_in, tr_temp_b, RBL*128);
    temp_in_mfma<<<dim3(56,4),256,0,stream>>>(AT, WtT, temp_in);
    k_f2b<<<cdiv_h(RBL*128,256),256,0,stream>>>(temp_in, tempB, RBL*128);

    // ---------------- temporal GAT ----------------
    mgemm<8,0,0,false,false><<<dim3(1,6),256,0,stream>>>(tempB, gtpWT, nullptr, nullptr,
                                                         hB, RBL, 128, 128);
    k_sc<<<cdiv_h(RBL,256),256,0,stream>>>(hB, gat_tp_as, gat_tp_ad, sc_s, sc_d, RBL);
    hipMemsetAsync(nsum, 0, (size_t)RBL*4*4, stream);
    k_attE<<<cdiv_h(B_*E_TP,256),256,0,stream>>>(sc_s, sc_d, ei_tp, E_TP, NT_, a_buf, nsum);
    k_gather<false><<<RBL/4,256,0,stream>>>(hB, a_buf, nsum, nullptr, ei_tp, off_tp, list_tp,
                                            gat_tp_b, embB, E_TP, NT_);
    mgemm<8,0,0,false,false><<<dim3(8,6),256,0,stream>>>(embB, w1catT_tp, b1cat_tp, nullptr,
                                                         PQ_t, RBL, 1024, 128);
    ext2_mfma<false><<<(B_*E_TP)/256,256,0,stream>>>(PQ_t, W2T_tp, ext_tp_b2, ext_tp_w3,
                                                     ext_tp_b3, ei_tp, att, E_TP, NT_,
                                                     (B_*E_TP)/256);
    k_gather<true><<<RBL/4,256,0,stream>>>(hB, a_buf, nsum, att, ei_tp, off_tp, list_tp,
                                           gat_tp_b, toutB, E_TP, NT_);

    // ---------------- temporal back-projection + ts_temp ----------------
    mgemm<4,0,0,false,false><<<dim3(883,6),256,0,stream>>>(toutB, itWT, inv_temp_b, nullptr,
                                                           tback, RBL, NDM, 128);
    mgemm<4,1,1,false,false><<<dim3(1,442),256,0,stream>>>(tback, tswT_hi, ts_b, nullptr,
                                                           ts_temp, RBN, 64, LDM);

    // ---------------- concat + residual MLP encoder (MFMA) + regression head ----------------
    k_hid<<<cdiv_h(RBN*320,256),256,0,stream>>>(ts_res, ts_temp, node_emb, tid_emb, diw_emb, hist,
                                                hid, hidB);
    for (int i = 0; i < 3; ++i) {
        mgemm<10,0,0,true,false><<<dim3(2,442),256,0,stream>>>(hidB, w1T_enc + (size_t)i*320*320,
                                                               enc_b1 + i*320, nullptr, R1b, RBN, 320, 320);
        mgemm<10,0,0,false,true><<<dim3(2,442),256,0,stream>>>(R1b, w2T_enc + (size_t)i*320*320,
                                                               enc_b2 + i*320, hid, hidB, RBN, 320, 320);
    }
    mgemm<1,0,2,false,false><<<dim3(1,442),256,0,stream>>>(hidB, reg_wT, reg_b, nullptr,
                                                           out, RBN, 16, 320);
}

// Round 9
// 1445.913 us; speedup vs baseline: 1.1590x; 1.1590x over previous
//
#include <hip/hip_runtime.h>
#include <hip/hip_bf16.h>
#include <cstdint>
#include <cstddef>

#define B_   32
#define L_   12
#define N_   883
#define DM_  64
#define E_SP 14128
#define E_TP 144
#define NT_  12
#define RBN  28256      // B*N
#define RBL  384        // B*L
#define LDM  768        // L*DM
#define NDM  56512      // N*DM

static inline int cdiv_h(int a, int b){ return (a+b-1)/b; }

// bf16 round-to-nearest-even from float
__device__ __forceinline__ ushort f2bf(float f){
    unsigned u = __float_as_uint(f);
    unsigned lsb = (u >> 16) & 1u;
    u += 0x7fffu + lsb;
    return (ushort)(u >> 16);
}
__device__ __forceinline__ float bf2f(ushort h){
    return __uint_as_float(((unsigned)h) << 16);
}

typedef __bf16 bf16x8 __attribute__((ext_vector_type(8)));
typedef float  f32x4  __attribute__((ext_vector_type(4)));
typedef short  s16x2  __attribute__((ext_vector_type(2)));
union BF8 { bf16x8 v; ushort u[8]; unsigned w[4]; int4 i; };

// packed relu on 2 bf16 (sign-magnitude => signed-i16 max-with-0 is exact relu)
__device__ __forceinline__ unsigned pkrelu(unsigned x){
    s16x2 v;
    __builtin_memcpy(&v, &x, 4);
    s16x2 z = 0;
    v = __builtin_elementwise_max(v, z);
    unsigned r;
    __builtin_memcpy(&r, &v, 4);
    return r;
}

// ============================ res: X = hist @ start_w + start_b (hi/lo bf16) ==============
__global__ void k_res(const float* __restrict__ hist, const float* __restrict__ sw,
                      const float* __restrict__ sb, ushort* __restrict__ resHi,
                      ushort* __restrict__ resLo)
{
    int idx = blockIdx.x*256 + threadIdx.x;
    if (idx >= RBN*LDM) return;
    int r = idx / LDM, col = idx - r*LDM;
    int b = r / N_, n = r - b*N_;
    int l = col >> 6, d = col & 63;
    const float* hp = hist + ((size_t)(b*L_ + l)*N_ + n)*3;
    float v = hp[0]*sw[d] + hp[1]*sw[64+d] + hp[2]*sw[128+d] + sb[d];
    ushort hi = f2bf(v);
    resHi[idx] = hi;
    resLo[idx] = f2bf(v - bf2f(hi));
}

// ============== generalized MFMA GEMM (direct-from-global), 1 row-tile/wave ==============
// A bf16. AMODE 0: A[r*K+k]. AMODE 1: r=(b*883+n), k=(l*64+d), addr (b*12+l)*56512 + n*64 + d.
// EPI 0: bf16 out[r*N+c]. EPI 1: f32 out[r*N+c]. EPI 2: head scatter f32 out[(b*12+c)*883+n], c<12.
// EPI 3: bf16 AT scatter out[(b*12+(c>>6))*56512 + n*64 + (c&63)].
// RES (EPI 0 only): v += resF[r*N+c], resF written back fp32.
template<int CT, int AMODE, int EPI, bool RELU, bool RES>
__launch_bounds__(256)
__global__ void mgemm(const ushort* __restrict__ A, const ushort* __restrict__ WT,
                      const float* __restrict__ bias, float* __restrict__ resF,
                      void* __restrict__ outP, int M, int N, int K)
{
    const int t = threadIdx.x, wv = t >> 6, l = t & 63;
    const int lr = l & 15, lk = l >> 4;
    const int row0 = blockIdx.y*64 + wv*16;
    const int col0 = blockIdx.x * (CT*16);
    int arr = row0 + lr; if (arr >= M) arr = M-1;
    int ab = 0, an = 0;
    if (AMODE == 1) { ab = arr / N_; an = arr - ab*N_; }
    const ushort* ap = A + (size_t)arr*K + lk*8;
    f32x4 acc[CT] = {};
    for (int k0 = 0; k0 < K; k0 += 32) {
        BF8 af;
        if (AMODE == 0) af.i = *(const int4*)(ap + k0);
        else {
            int k = k0 + lk*8; int ll = k >> 6, d = k & 63;
            af.i = *(const int4*)(A + ((size_t)(ab*L_ + ll))*NDM + (size_t)an*64 + d);
        }
        #pragma unroll
        for (int ct = 0; ct < CT; ++ct) {
            BF8 bf; bf.i = *(const int4*)&WT[(size_t)(col0 + ct*16 + lr)*K + k0 + lk*8];
            acc[ct] = __builtin_amdgcn_mfma_f32_16x16x32_bf16(af.v, bf.v, acc[ct], 0, 0, 0);
        }
    }
    #pragma unroll
    for (int ct = 0; ct < CT; ++ct) {
        int c = col0 + ct*16 + lr;
        float bv = 0.f;
        if (EPI == 2) { if (bias && c < 12) bv = bias[c]; }
        else if (bias) bv = bias[c];
        #pragma unroll
        for (int g = 0; g < 4; ++g) {
            int r = row0 + lk*4 + g;
            if (r >= M) continue;
            float v = acc[ct][g] + bv;
            if (RELU) v = fmaxf(v, 0.f);
            if (RES) {
                v += resF[(size_t)r*N + c];
                resF[(size_t)r*N + c] = v;
            }
            if (EPI == 0) {
                ((ushort*)outP)[(size_t)r*N + c] = f2bf(v);
            } else if (EPI == 1) {
                ((float*)outP)[(size_t)r*N + c] = v;
            } else if (EPI == 2) {
                if (c < 12) {
                    int b = r / N_, n = r - (r/N_)*N_;
                    ((float*)outP)[((size_t)(b*L_ + c))*N_ + n] = v;
                }
            } else {
                int b = r / N_, n = r - (r/N_)*N_;
                ((ushort*)outP)[((size_t)(b*L_ + (c>>6)))*NDM + (size_t)n*64 + (c&63)] = f2bf(v);
            }
        }
    }
}

// ============== MFMA GEMM with RT row-tiles/wave (B-load amortization) ==============
// Streaming A only (AMODE 0 layout). Rows/block = 4 waves * RT * 16.
// Per kc: RT A-loads + CT B-loads feed RT*CT MFMAs (vs 1+CT for mgemm) — cuts the
// vmem-per-MFMA ratio that R7's post-mortem showed is the limiter for these GEMMs.
template<int RT, int CT, int EPI, bool RELU, bool RES>
__launch_bounds__(256)
__global__ void mgemm_rt(const ushort* __restrict__ A, const ushort* __restrict__ WT,
                         const float* __restrict__ bias, float* __restrict__ resF,
                         void* __restrict__ outP, int M, int N, int K)
{
    const int t = threadIdx.x, wv = t >> 6, l = t & 63;
    const int lr = l & 15, lk = l >> 4;
    const int rowbase = blockIdx.y*(4*RT*16) + wv*(RT*16);
    const int col0 = blockIdx.x * (CT*16);
    const ushort* ap[RT];
    #pragma unroll
    for (int rt = 0; rt < RT; ++rt) {
        int arr = rowbase + rt*16 + lr; if (arr >= M) arr = M-1;
        ap[rt] = A + (size_t)arr*K + lk*8;
    }
    f32x4 acc[RT][CT] = {};
    for (int k0 = 0; k0 < K; k0 += 32) {
        BF8 af[RT];
        #pragma unroll
        for (int rt = 0; rt < RT; ++rt) af[rt].i = *(const int4*)(ap[rt] + k0);
        #pragma unroll
        for (int ct = 0; ct < CT; ++ct) {
            BF8 bf; bf.i = *(const int4*)&WT[(size_t)(col0 + ct*16 + lr)*K + k0 + lk*8];
            #pragma unroll
            for (int rt = 0; rt < RT; ++rt)
                acc[rt][ct] = __builtin_amdgcn_mfma_f32_16x16x32_bf16(af[rt].v, bf.v,
                                                                     acc[rt][ct], 0, 0, 0);
        }
    }
    #pragma unroll
    for (int rt = 0; rt < RT; ++rt)
        #pragma unroll
        for (int ct = 0; ct < CT; ++ct) {
            int c = col0 + ct*16 + lr;
            float bv = bias ? bias[c] : 0.f;
            #pragma unroll
            for (int g = 0; g < 4; ++g) {
                int r = rowbase + rt*16 + lk*4 + g;
                if (r >= M) continue;
                float v = acc[rt][ct][g] + bv;
                if (RELU) v = fmaxf(v, 0.f);
                if (RES) {
                    v += resF[(size_t)r*N + c];
                    resF[(size_t)r*N + c] = v;
                }
                if (EPI == 0) {
                    ((ushort*)outP)[(size_t)r*N + c] = f2bf(v);
                } else if (EPI == 1) {
                    ((float*)outP)[(size_t)r*N + c] = v;
                } else {  // EPI 3: bf16 AT scatter
                    int b = r / N_, n = r - (r/N_)*N_;
                    ((ushort*)outP)[((size_t)(b*L_ + (c>>6)))*NDM + (size_t)n*64 + (c&63)] = f2bf(v);
                }
            }
        }
}

// ============== hi/lo split MFMA GEMM (near-fp32 precision), fp32 out ==============
template<int CT>
__launch_bounds__(256)
__global__ void mgemm_hl(const ushort* __restrict__ Ahi, const ushort* __restrict__ Alo,
                         const ushort* __restrict__ WThi, const ushort* __restrict__ WTlo,
                         const float* __restrict__ bias, float* __restrict__ outF,
                         int M, int N, int K)
{
    const int t = threadIdx.x, wv = t >> 6, l = t & 63;
    const int lr = l & 15, lk = l >> 4;
    const int row0 = blockIdx.y*64 + wv*16;
    const int col0 = blockIdx.x * (CT*16);
    int arr = row0 + lr; if (arr >= M) arr = M-1;
    const ushort* aph = Ahi + (size_t)arr*K + lk*8;
    const ushort* apl = Alo + (size_t)arr*K + lk*8;
    f32x4 acc[CT] = {};
    for (int k0 = 0; k0 < K; k0 += 32) {
        BF8 ah, al_;
        ah.i  = *(const int4*)(aph + k0);
        al_.i = *(const int4*)(apl + k0);
        #pragma unroll
        for (int ct = 0; ct < CT; ++ct) {
            size_t wo = (size_t)(col0 + ct*16 + lr)*K + k0 + lk*8;
            BF8 bh, bl;
            bh.i = *(const int4*)&WThi[wo];
            bl.i = *(const int4*)&WTlo[wo];
            acc[ct] = __builtin_amdgcn_mfma_f32_16x16x32_bf16(ah.v,  bh.v, acc[ct], 0, 0, 0);
            acc[ct] = __builtin_amdgcn_mfma_f32_16x16x32_bf16(al_.v, bh.v, acc[ct], 0, 0, 0);
            acc[ct] = __builtin_amdgcn_mfma_f32_16x16x32_bf16(ah.v,  bl.v, acc[ct], 0, 0, 0);
        }
    }
    #pragma unroll
    for (int ct = 0; ct < CT; ++ct) {
        int c = col0 + ct*16 + lr;
        float bv = bias ? bias[c] : 0.f;
        #pragma unroll
        for (int g = 0; g < 4; ++g) {
            int r = row0 + lk*4 + g;
            if (r >= M) continue;
            outF[(size_t)r*N + c] = acc[ct][g] + bv;
        }
    }
}

// ============== temp_in via split-K MFMA: out[384][128] += AT @ WtT^T ==============
#define TCH 1024
__launch_bounds__(256)
__global__ void temp_in_mfma(const ushort* __restrict__ AT, const ushort* __restrict__ WtT,
                             float* __restrict__ out)
{
    const int t = threadIdx.x, wv = t >> 6, l = t & 63;
    const int lr = l & 15, lk = l >> 4;
    const int row0 = blockIdx.y * 96;
    const int c0 = wv * 32;
    const int k0b = blockIdx.x * TCH;
    const int kend = (k0b + TCH < NDM) ? (k0b + TCH) : NDM;
    f32x4 acc[6][2] = {};
    for (int k0 = k0b; k0 < kend; k0 += 32) {
        BF8 b0, b1;
        b0.i = *(const int4*)&WtT[(size_t)(c0 + lr)*NDM + k0 + lk*8];
        b1.i = *(const int4*)&WtT[(size_t)(c0 + 16 + lr)*NDM + k0 + lk*8];
        #pragma unroll
        for (int m = 0; m < 6; ++m) {
            BF8 af; af.i = *(const int4*)&AT[(size_t)(row0 + m*16 + lr)*NDM + k0 + lk*8];
            acc[m][0] = __builtin_amdgcn_mfma_f32_16x16x32_bf16(af.v, b0.v, acc[m][0], 0, 0, 0);
            acc[m][1] = __builtin_amdgcn_mfma_f32_16x16x32_bf16(af.v, b1.v, acc[m][1], 0, 0, 0);
        }
    }
    #pragma unroll
    for (int m = 0; m < 6; ++m)
        #pragma unroll
        for (int ct = 0; ct < 2; ++ct) {
            int c = c0 + ct*16 + lr;
            #pragma unroll
            for (int g = 0; g < 4; ++g) {
                int r = row0 + m*16 + lk*4 + g;
                atomicAdd(&out[(size_t)r*128 + c], acc[m][ct][g]);
            }
        }
}

// ============================ attention scores (bf16 h) ============================
__global__ void k_sc(const ushort* __restrict__ h, const float* __restrict__ as_,
                     const float* __restrict__ ad_, float* __restrict__ scs,
                     float* __restrict__ scd, int R)
{
    int r = blockIdx.x*256 + threadIdx.x;
    if (r >= R) return;
    const ushort* hr = h + (size_t)r*128;
    #pragma unroll
    for (int hh = 0; hh < 4; ++hh) {
        float ss = 0.f, sd = 0.f;
        #pragma unroll
        for (int k = 0; k < 32; ++k) {
            float hv = bf2f(hr[hh*32 + k]);
            ss += hv*as_[hh*32+k];
            sd += hv*ad_[hh*32+k];
        }
        scs[(size_t)r*4+hh] = ss;
        scd[(size_t)r*4+hh] = sd;
    }
}

// ================= edge softmax (no max-sub: logits are O(1), exp cannot overflow) ========
__global__ void k_attE(const float* __restrict__ scs, const float* __restrict__ scd,
                       const int* __restrict__ ei, int E, int NN,
                       float* __restrict__ a_buf, float* __restrict__ nsum)
{
    int idx = blockIdx.x*256 + threadIdx.x;
    if (idx >= B_*E) return;
    int b = idx / E, e = idx - b*E;
    int s = ei[e], tg = ei[E+e];
    const float* ps = scs + (size_t)(b*NN+s)*4;
    const float* pd = scd + (size_t)(b*NN+tg)*4;
    float* ns = nsum + (size_t)(b*NN+tg)*4;
    float* pa = a_buf + (size_t)idx*4;
    #pragma unroll
    for (int hh = 0; hh < 4; ++hh) {
        float al = ps[hh] + pd[hh];
        al = al > 0.f ? al : 0.2f*al;
        float ex = expf(al);
        pa[hh] = ex;
        atomicAdd(ns + hh, ex);
    }
}

// ============================ CSR build (target-indexed) ============================
__global__ void k_count(const int* __restrict__ ei, int E, int* __restrict__ counts){
    int e = blockIdx.x*256 + threadIdx.x;
    if (e < E) atomicAdd(&counts[ei[E + e]], 1);
}
__global__ void k_scan(const int* __restrict__ counts, int* __restrict__ off,
                       int* __restrict__ cur, int n)
{
    __shared__ int s[1024];
    int t = threadIdx.x;
    int v0 = (t < n) ? counts[t] : 0;
    s[t] = v0;
    __syncthreads();
    for (int o = 1; o < 1024; o <<= 1) {
        int v = (t >= o) ? s[t-o] : 0;
        __syncthreads();
        s[t] += v;
        __syncthreads();
    }
    if (t < n) {
        off[t+1] = s[t];
        cur[t] = s[t] - v0;
        if (t == 0) off[0] = 0;
    }
}
__global__ void k_fill(const int* __restrict__ ei, int E, int* __restrict__ cur,
                       int* __restrict__ lst){
    int e = blockIdx.x*256 + threadIdx.x;
    if (e < E) {
        int pos = atomicAdd(&cur[ei[E+e]], 1);
        lst[pos] = e;
    }
}

// ====================== GAT aggregation (4 waves/block, one wave per (b,n)) ==============
template<bool USE_ATT>
__global__ void k_gather(const ushort* __restrict__ h, const float* __restrict__ a_buf,
                         const float* __restrict__ nsum, const float* __restrict__ att,
                         const int* __restrict__ ei, const int* __restrict__ off,
                         const int* __restrict__ lst, const float* __restrict__ bias,
                         ushort* __restrict__ out, int E, int NN)
{
    int bn = blockIdx.x*4 + (threadIdx.x >> 6);
    int b = bn / NN, n = bn - b*NN;
    int lane = threadIdx.x & 63;
    int c0 = lane*2;
    int hh = lane >> 4;
    float rn = 1.f / nsum[(size_t)bn*4 + hh];
    int o0 = off[n], o1 = off[n+1];
    float ax = 0.f, ay = 0.f;
    for (int i = o0; i < o1; ++i) {
        int e = lst[i];
        float a = a_buf[((size_t)b*E + e)*4 + hh] * rn;
        if (USE_ATT) a *= att[(size_t)b*E + e];
        int s = ei[e];
        unsigned hv = *(const unsigned*)&h[((size_t)b*NN + s)*128 + c0];
        ax += a * __uint_as_float(hv << 16);
        ay += a * __uint_as_float(hv & 0xffff0000u);
    }
    ushort2 o2;
    o2.x = f2bf(ax + bias[c0]);
    o2.y = f2bf(ay + bias[c0+1]);
    *(ushort2*)&out[(size_t)bn*128 + c0] = o2;
}

// ============================ weight prep kernels ============================
__global__ void k_prepW2(const float* __restrict__ W2, ushort* __restrict__ W2T)
{
    int idx = blockIdx.x*256 + threadIdx.x;   // 512*128
    if (idx >= 512*128) return;
    int k = idx >> 7, c = idx & 127;
    W2T[(size_t)c*512 + k] = f2bf(W2[idx]);
}
// generic W[K][N] -> WT[N][K] bf16
__global__ void k_prepT(const float* __restrict__ W, ushort* __restrict__ WT, int K, int N)
{
    int idx = blockIdx.x*256 + threadIdx.x;
    if (idx >= K*N) return;
    int k = idx / N, c = idx - k*N;
    WT[(size_t)c*K + k] = f2bf(W[idx]);
}
// W[K][N] -> hi/lo transposed
__global__ void k_prepT_hl(const float* __restrict__ W, ushort* __restrict__ WThi,
                           ushort* __restrict__ WTlo, int K, int N)
{
    int idx = blockIdx.x*256 + threadIdx.x;
    if (idx >= K*N) return;
    int k = idx / N, c = idx - k*N;
    float v = W[idx];
    ushort hi = f2bf(v);
    WThi[(size_t)c*K + k] = hi;
    WTlo[(size_t)c*K + k] = f2bf(v - bf2f(hi));
}
// tr_temp_w [56512][128] -> WtT [128][56512] bf16 (tiled)
__global__ void k_prepWtT(const float* __restrict__ W, ushort* __restrict__ WT)
{
    __shared__ ushort tile[128][129];
    int k0 = blockIdx.x * 128;
    int t = threadIdx.x;
    for (int i = t; i < 128*128; i += 256) {
        int k = i >> 7, c = i & 127;
        int kk = k0 + k;
        tile[c][k] = (kk < NDM) ? f2bf(W[(size_t)kk*128 + c]) : (ushort)0;
    }
    __syncthreads();
    for (int i = t; i < 128*128; i += 256) {
        int c = i >> 7, k = i & 127;
        int kk = k0 + k;
        if (kk < NDM) WT[(size_t)c*NDM + kk] = tile[c][k];
    }
}
// inv_temp_w [128][56512] -> WT [56512][128] bf16 (tiled, 64 cols/block)
__global__ void k_prepT_big(const float* __restrict__ W, ushort* __restrict__ WT)
{
    __shared__ float tile[128][65];
    int c0 = blockIdx.x * 64;
    int t = threadIdx.x;
    for (int i = t; i < 128*64; i += 256) {
        int k = i >> 6, ci = i & 63;
        tile[k][ci] = W[(size_t)k*NDM + c0 + ci];
    }
    __syncthreads();
    for (int i = t; i < 64*128; i += 256) {
        int ci = i >> 7, k = i & 127;
        WT[(size_t)(c0 + ci)*128 + k] = f2bf(tile[k][ci]);
    }
}
// bias concat: [b1, zeros]
__global__ void k_bcat(const float* __restrict__ b1, float* __restrict__ dst){
    int i = blockIdx.x*256 + threadIdx.x;
    if (i < 1024) dst[i] = (i < 512) ? b1[i] : 0.f;
}

// ======== MFMA fused extractor stage2 (R6 version — best measured at 145 us) =====
// Software-pipelined, single barrier per k-chunk. att = sigmoid(relu(relu(P[es]+Q[et])@W2+b2)@w3+b3).
// PQ: bf16 [rows][1024] (P cols 0-511, Q cols 512-1023). W2T: bf16 [128 cols][512 k].
// 256 edge-rows/block, 4 waves, 4 row-tiles/wave, 8 col-tiles. A(kc) held in regs (loaded at
// kc-1); B double-buffered through regs into alternating LDS halves. One __syncthreads per kc.
// LDS staging amortizes B across the block's 4 waves (R7 post-mortem: per-wave B reload is
// vmem-issue-bound and 1.57x slower).
template<bool SWZ>
__launch_bounds__(256, 2)
__global__ void ext2_mfma(const ushort* __restrict__ PQ, const ushort* __restrict__ W2T,
                          const float* __restrict__ b2, const float* __restrict__ w3,
                          const float* __restrict__ b3p, const int* __restrict__ ei,
                          float* __restrict__ att, int E, int NN, int nblk)
{
    __shared__ ushort Bs[2][128*40];
    int bid = blockIdx.x;
    if (SWZ) {
        bid = (blockIdx.x & 7) * (gridDim.x >> 3) + (blockIdx.x >> 3);
        if (bid >= nblk) bid = nblk - 1;
    }
    const int t = threadIdx.x;
    const int wv = t >> 6, l = t & 63;
    const int lr = l & 15, lk = l >> 4;

    const ushort* pr[4]; const ushort* qr[4];
    int row0[4];
    #pragma unroll
    for (int rt = 0; rt < 4; ++rt) {
        row0[rt] = bid*256 + wv*64 + rt*16;
        int r = row0[rt] + lr;
        int b = r / E, e = r - b*E;
        pr[rt] = PQ + ((size_t)b*NN + ei[e])*1024 + lk*8;
        qr[rt] = PQ + ((size_t)b*NN + ei[E+e])*1024 + 512 + lk*8;
    }
    // B staging: thread t owns col t>>1, 16-ushort half (t&1)
    const int sc = t >> 1, sh = (t & 1) * 16;
    const ushort* wsrc = W2T + (size_t)sc*512 + sh;
    ushort* wd0 = &Bs[0][sc*40 + sh];
    ushort* wd1 = &Bs[1][sc*40 + sh];

    // prologue: B(0)->LDS[0]; B(1)->regs; A(0)->regs
    {
        int4 a0 = *(const int4*)(wsrc);
        int4 a1 = *(const int4*)(wsrc + 8);
        *(int4*)wd0 = a0;
        *(int4*)(wd0 + 8) = a1;
    }
    int4 bnA = *(const int4*)(wsrc + 32);
    int4 bnB = *(const int4*)(wsrc + 40);
    BF8 pu[4], qu[4];
    #pragma unroll
    for (int rt = 0; rt < 4; ++rt) {
        pu[rt].i = *(const int4*)(pr[rt]);
        qu[rt].i = *(const int4*)(qr[rt]);
    }
    __syncthreads();

    f32x4 acc[4][8] = {};
    for (int kc = 0; kc < 16; ++kc) {
        const int cb = kc & 1;
        // repack A(kc) from held regs
        BF8 af[4];
        #pragma unroll
        for (int rt = 0; rt < 4; ++rt)
            #pragma unroll
            for (int j = 0; j < 4; ++j) {
                unsigned up = pu[rt].w[j], uq = qu[rt].w[j];
                float rlo = __uint_as_float(up << 16)         + __uint_as_float(uq << 16);
                float rhi = __uint_as_float(up & 0xffff0000u) + __uint_as_float(uq & 0xffff0000u);
                unsigned pk = __builtin_amdgcn_perm(__float_as_uint(rhi), __float_as_uint(rlo),
                                                    0x07060302u);
                af[rt].w[j] = pkrelu(pk);
            }
        // stage B(kc+1) regs -> LDS[cb^1]  (safe: all waves passed barrier ending iter kc-1)
        if (kc < 15) {
            ushort* wd = cb ? wd0 : wd1;
            *(int4*)wd = bnA;
            *(int4*)(wd + 8) = bnB;
        }
        // issue next global loads (clamped; redundant tail loads harmless)
        {
            int ka = (kc+1 < 15) ? kc+1 : 15;
            int kb = (kc+2 < 15) ? kc+2 : 15;
            bnA = *(const int4*)(wsrc + kb*32);
            bnB = *(const int4*)(wsrc + kb*32 + 8);
            #pragma unroll
            for (int rt = 0; rt < 4; ++rt) {
                pu[rt].i = *(const int4*)(pr[rt] + ka*32);
                qu[rt].i = *(const int4*)(qr[rt] + ka*32);
            }
        }
        // MFMA on LDS[cb]
        #pragma unroll
        for (int ct = 0; ct < 8; ++ct) {
            BF8 bfm;
            bfm.v = *(const bf16x8*)&Bs[cb][(ct*16 + lr)*40 + lk*8];
            #pragma unroll
            for (int rt = 0; rt < 4; ++rt)
                acc[rt][ct] = __builtin_amdgcn_mfma_f32_16x16x32_bf16(af[rt].v, bfm.v,
                                                                     acc[rt][ct], 0, 0, 0);
        }
        __syncthreads();
    }
    float b3 = b3p[0];
    #pragma unroll
    for (int rt = 0; rt < 4; ++rt) {
        float part[4] = {0.f,0.f,0.f,0.f};
        #pragma unroll
        for (int ct = 0; ct < 8; ++ct) {
            int c = ct*16 + lr;
            float b2v = b2[c], w3v = w3[c];
            #pragma unroll
            for (int g = 0; g < 4; ++g)
                part[g] += fmaxf(acc[rt][ct][g] + b2v, 0.f) * w3v;
        }
        #pragma unroll
        for (int m = 1; m < 16; m <<= 1)
            #pragma unroll
            for (int g = 0; g < 4; ++g)
                part[g] += __shfl_xor(part[g], m, 64);
        if (lr == 0) {
            #pragma unroll
            for (int g = 0; g < 4; ++g) {
                int rr = row0[rt] + lk*4 + g;
                att[rr] = 1.f/(1.f + expf(-(part[g] + b3)));
            }
        }
    }
}

// ============================ misc ============================
__global__ void k_bias_fill(float* __restrict__ dst, const float* __restrict__ bias, int n){
    int i = blockIdx.x*256 + threadIdx.x;
    if (i < n) dst[i] = bias[i & 127];
}
__global__ void k_f2b(const float* __restrict__ src, ushort* __restrict__ dst, int n){
    int i = blockIdx.x*256 + threadIdx.x;
    if (i < n) dst[i] = f2bf(src[i]);
}

// ============================ hid concat (fp32 + bf16 shadow) ============================
__global__ void k_hid(const float* __restrict__ ts_res, const float* __restrict__ ts_temp,
                      const float* __restrict__ node_emb, const float* __restrict__ tid_emb,
                      const float* __restrict__ diw_emb, const float* __restrict__ hist,
                      float* __restrict__ hid, ushort* __restrict__ hidB)
{
    int idx = blockIdx.x*256 + threadIdx.x;
    if (idx >= RBN*320) return;
    int r = idx / 320, c = idx - r*320;
    int b = r / N_, n = r - b*N_;
    float v;
    if (c < 64)        v = ts_res[(size_t)r*64 + c];
    else if (c < 128)  v = ts_temp[(size_t)r*64 + (c-64)];
    else if (c < 192)  v = node_emb[(size_t)n*64 + (c-128)];
    else if (c < 256) {
        int tid = (int)hist[((size_t)(b*L_ + (L_-1))*N_ + n)*3 + 1];
        v = tid_emb[(size_t)tid*64 + (c-192)];
    } else {
        int diw = (int)hist[((size_t)(b*L_ + (L_-1))*N_ + n)*3 + 2];
        v = diw_emb[(size_t)diw*64 + (c-256)];
    }
    hid[idx] = v;
    hidB[idx] = f2bf(v);
}

// =====================================================================================
extern "C" void kernel_launch(void* const* d_in, const int* in_sizes, int n_in,
                              void* d_out, int out_size, void* d_ws, size_t ws_size,
                              hipStream_t stream)
{
    (void)in_sizes; (void)n_in; (void)out_size; (void)ws_size;
    const float* hist      = (const float*)d_in[0];
    const int*   ei_sp     = (const int*)  d_in[1];
    const int*   ei_tp     = (const int*)  d_in[2];
    const float* node_emb  = (const float*)d_in[3];
    const float* tid_emb   = (const float*)d_in[4];
    const float* diw_emb   = (const float*)d_in[5];
    const float* start_w   = (const float*)d_in[6];
    const float* start_b   = (const float*)d_in[7];
    const float* ts_w      = (const float*)d_in[8];
    const float* ts_b      = (const float*)d_in[9];
    const float* tr_spat_w = (const float*)d_in[10];
    const float* tr_spat_b = (const float*)d_in[11];
    const float* inv_spat_w= (const float*)d_in[12];
    const float* inv_spat_b= (const float*)d_in[13];
    const float* tr_temp_w = (const float*)d_in[14];
    const float* tr_temp_b = (const float*)d_in[15];
    const float* inv_temp_w= (const float*)d_in[16];
    const float* inv_temp_b= (const float*)d_in[17];
    const float* gat_sp_w  = (const float*)d_in[18];
    const float* gat_sp_as = (const float*)d_in[19];
    const float* gat_sp_ad = (const float*)d_in[20];
    const float* gat_sp_b  = (const float*)d_in[21];
    const float* ext_sp_w1 = (const float*)d_in[22];
    const float* ext_sp_b1 = (const float*)d_in[23];
    const float* ext_sp_w2 = (const float*)d_in[24];
    const float* ext_sp_b2 = (const float*)d_in[25];
    const float* ext_sp_w3 = (const float*)d_in[26];
    const float* ext_sp_b3 = (const float*)d_in[27];
    const float* gat_tp_w  = (const float*)d_in[28];
    const float* gat_tp_as = (const float*)d_in[29];
    const float* gat_tp_ad = (const float*)d_in[30];
    const float* gat_tp_b  = (const float*)d_in[31];
    const float* ext_tp_w1 = (const float*)d_in[32];
    const float* ext_tp_b1 = (const float*)d_in[33];
    const float* ext_tp_w2 = (const float*)d_in[34];
    const float* ext_tp_b2 = (const float*)d_in[35];
    const float* ext_tp_w3 = (const float*)d_in[36];
    const float* ext_tp_b3 = (const float*)d_in[37];
    const float* enc_w1    = (const float*)d_in[38];
    const float* enc_b1    = (const float*)d_in[39];
    const float* enc_w2    = (const float*)d_in[40];
    const float* enc_b2    = (const float*)d_in[41];
    const float* reg_w     = (const float*)d_in[42];
    const float* reg_b     = (const float*)d_in[43];
    float* out = (float*)d_out;

    // ---------------- workspace layout (byte-granular, 256B aligned) ----------------
    size_t o = 0;
    char* wsb = (char*)d_ws;
    auto allocB = [&](size_t bytes) -> void* {
        void* p = wsb + o;
        o += (bytes + 255) & ~(size_t)255;
        return p;
    };
    // big reusable arenas
    void* bufA = allocB((size_t)RBN*768*2);   // resHi -> AT[384][56512]bf16 -> hid fp32[RBN][320]
    void* bufB = allocB((size_t)RBN*768*2);   // resLo -> PQ_sp[RBN][1024]bf16 (spills into bufC) -> tback
    void* bufC = allocB((size_t)RBN*512*2);   // (PQ_sp tail) -> hidB[RBN][320]bf16
    void* bufD = allocB((size_t)RBN*320*2);   // R1b (encoder temp bf16)
    float*  ts_res  = (float*)allocB((size_t)RBN*64*4);
    ushort* spaB    = (ushort*)allocB((size_t)RBN*128*2);  // spa_in -> spa_out
    ushort* hB      = (ushort*)allocB((size_t)RBN*128*2);  // h_sp -> h_tp
    float*  sc_s    = (float*)allocB((size_t)RBN*4*4);
    float*  sc_d    = (float*)allocB((size_t)RBN*4*4);
    float*  nsum    = (float*)allocB((size_t)RBN*4*4);
    float*  a_buf   = (float*)allocB((size_t)B_*E_SP*4*4);
    float*  att     = (float*)allocB((size_t)B_*E_SP*4);
    ushort* embB    = (ushort*)allocB((size_t)RBN*128*2);
    int*    csr     = (int*)allocB(17024*4);
    float*  temp_in = (float*)allocB((size_t)RBL*128*4);
    ushort* tempB   = (ushort*)allocB((size_t)RBL*128*2);
    ushort* toutB   = (ushort*)allocB((size_t)RBL*128*2);
    ushort* PQ_t    = (ushort*)allocB((size_t)RBL*1024*2);
    float*  ts_temp = (float*)allocB((size_t)RBN*64*4);
    // weight preps
    ushort* W2T_sp  = (ushort*)allocB(512*128*2);
    ushort* W2T_tp  = (ushort*)allocB(512*128*2);
    ushort* WtT     = (ushort*)allocB((size_t)128*NDM*2);   // tr_temp_w^T
    ushort* itWT    = (ushort*)allocB((size_t)NDM*128*2);   // inv_temp_w^T
    ushort* tspWT   = (ushort*)allocB(128*768*2);           // tr_spat_w^T
    ushort* ispWT   = (ushort*)allocB(768*128*2);           // inv_spat_w^T
    ushort* gspWT   = (ushort*)allocB(128*128*2);
    ushort* gtpWT   = (ushort*)allocB(128*128*2);
    ushort* w1catT_sp = (ushort*)allocB((size_t)1024*128*2);
    ushort* w1catT_tp = (ushort*)allocB((size_t)1024*128*2);
    float*  b1cat_sp  = (float*)allocB(1024*4);
    float*  b1cat_tp  = (float*)allocB(1024*4);
    ushort* w1T_enc = (ushort*)allocB((size_t)3*320*320*2);
    ushort* w2T_enc = (ushort*)allocB((size_t)3*320*320*2);
    ushort* tswT_hi = (ushort*)allocB(64*768*2);
    ushort* tswT_lo = (ushort*)allocB(64*768*2);
    ushort* reg_wT  = (ushort*)allocB(16*320*2);

    ushort* resHi = (ushort*)bufA;
    ushort* resLo = (ushort*)bufB;
    ushort* AT    = (ushort*)bufA;    // [384][56512]
    float*  hid   = (float*)bufA;     // [RBN][320] fp32
    ushort* PQ_sp = (ushort*)bufB;    // [RBN][1024] (57.9 MB, spans bufB+bufC)
    ushort* tback = (ushort*)bufB;    // [384][56512]
    ushort* hidB  = (ushort*)bufC;
    ushort* R1b   = (ushort*)bufD;

    int* counts_sp = csr;
    int* off_sp    = csr + 883;
    int* cur_sp    = csr + 1767;
    int* list_sp   = csr + 2650;
    int* counts_tp = csr + 16778;
    int* off_tp    = csr + 16790;
    int* cur_tp    = csr + 16803;
    int* list_tp   = csr + 16815;

    // ---------------- CSR builds + weight prep ----------------
    hipMemsetAsync(counts_sp, 0, 883*4, stream);
    k_count<<<cdiv_h(E_SP,256),256,0,stream>>>(ei_sp, E_SP, counts_sp);
    k_scan<<<1,1024,0,stream>>>(counts_sp, off_sp, cur_sp, 883);
    k_fill<<<cdiv_h(E_SP,256),256,0,stream>>>(ei_sp, E_SP, cur_sp, list_sp);
    hipMemsetAsync(counts_tp, 0, 12*4, stream);
    k_count<<<1,256,0,stream>>>(ei_tp, E_TP, counts_tp);
    k_scan<<<1,1024,0,stream>>>(counts_tp, off_tp, cur_tp, 12);
    k_fill<<<1,256,0,stream>>>(ei_tp, E_TP, cur_tp, list_tp);
    k_prepW2<<<cdiv_h(512*128,256),256,0,stream>>>(ext_sp_w2, W2T_sp);
    k_prepW2<<<cdiv_h(512*128,256),256,0,stream>>>(ext_tp_w2, W2T_tp);
    k_prepWtT<<<cdiv_h(NDM,128),256,0,stream>>>(tr_temp_w, WtT);
    k_prepT_big<<<NDM/64,256,0,stream>>>(inv_temp_w, itWT);
    k_prepT<<<cdiv_h(768*128,256),256,0,stream>>>(tr_spat_w, tspWT, 768, 128);
    k_prepT<<<cdiv_h(128*768,256),256,0,stream>>>(inv_spat_w, ispWT, 128, 768);
    k_prepT<<<cdiv_h(128*128,256),256,0,stream>>>(gat_sp_w, gspWT, 128, 128);
    k_prepT<<<cdiv_h(128*128,256),256,0,stream>>>(gat_tp_w, gtpWT, 128, 128);
    k_prepT<<<cdiv_h(128*512,256),256,0,stream>>>(ext_sp_w1,           w1catT_sp,           128, 512);
    k_prepT<<<cdiv_h(128*512,256),256,0,stream>>>(ext_sp_w1 + 128*512, w1catT_sp + 512*128, 128, 512);
    k_prepT<<<cdiv_h(128*512,256),256,0,stream>>>(ext_tp_w1,           w1catT_tp,           128, 512);
    k_prepT<<<cdiv_h(128*512,256),256,0,stream>>>(ext_tp_w1 + 128*512, w1catT_tp + 512*128, 128, 512);
    k_bcat<<<4,256,0,stream>>>(ext_sp_b1, b1cat_sp);
    k_bcat<<<4,256,0,stream>>>(ext_tp_b1, b1cat_tp);
    for (int i = 0; i < 3; ++i) {
        k_prepT<<<cdiv_h(320*320,256),256,0,stream>>>(enc_w1 + (size_t)i*320*320, w1T_enc + (size_t)i*320*320, 320, 320);
        k_prepT<<<cdiv_h(320*320,256),256,0,stream>>>(enc_w2 + (size_t)i*320*320, w2T_enc + (size_t)i*320*320, 320, 320);
    }
    k_prepT_hl<<<cdiv_h(768*64,256),256,0,stream>>>(ts_w, tswT_hi, tswT_lo, 768, 64);
    hipMemsetAsync(reg_wT, 0, 16*320*2, stream);
    k_prepT<<<cdiv_h(320*12,256),256,0,stream>>>(reg_w, reg_wT, 320, 12);

    // ---------------- res (hi/lo) / ts_res (hi-lo MFMA) / spa_in ----------------
    k_res<<<cdiv_h(RBN*LDM,256),256,0,stream>>>(hist, start_w, start_b, resHi, resLo);
    mgemm_hl<4><<<dim3(1,442),256,0,stream>>>(resHi, resLo, tswT_hi, tswT_lo, ts_b, ts_res,
                                              RBN, 64, LDM);
    mgemm_rt<2,4,0,false,false><<<dim3(2,221),256,0,stream>>>(resHi, tspWT, tr_spat_b, nullptr,
                                                              spaB, RBN, 128, LDM);

    // ---------------- spatial GAT ----------------
    mgemm_rt<2,4,0,false,false><<<dim3(2,221),256,0,stream>>>(spaB, gspWT, nullptr, nullptr,
                                                              hB, RBN, 128, 128);
    k_sc<<<cdiv_h(RBN,256),256,0,stream>>>(hB, gat_sp_as, gat_sp_ad, sc_s, sc_d, RBN);
    hipMemsetAsync(nsum, 0, (size_t)RBN*4*4, stream);
    k_attE<<<cdiv_h(B_*E_SP,256),256,0,stream>>>(sc_s, sc_d, ei_sp, E_SP, N_, a_buf, nsum);
    k_gather<false><<<RBN/4,256,0,stream>>>(hB, a_buf, nsum, nullptr, ei_sp, off_sp, list_sp,
                                            gat_sp_b, embB, E_SP, N_);
    // extractor: PQ = emb@[W1a|W1b] + [b1|0] (bf16); att = sigmoid(MLP) via MFMA
    mgemm_rt<2,8,0,false,false><<<dim3(8,221),256,0,stream>>>(embB, w1catT_sp, b1cat_sp, nullptr,
                                                              PQ_sp, RBN, 1024, 128);
    ext2_mfma<true><<<1768,256,0,stream>>>(PQ_sp, W2T_sp, ext_sp_b2, ext_sp_w3, ext_sp_b3,
                                           ei_sp, att, E_SP, N_, (B_*E_SP)/256);
    k_gather<true><<<RBN/4,256,0,stream>>>(hB, a_buf, nsum, att, ei_sp, off_sp, list_sp,
                                           gat_sp_b, spaB, E_SP, N_);

    // ---------------- back-projection (bf16 AT) + temporal input (MFMA split-K) ----------
    mgemm_rt<2,4,3,false,false><<<dim3(12,221),256,0,stream>>>(spaB, ispWT, inv_spat_b, nullptr,
                                                               AT, RBN, 768, 128);
    k_bias_fill<<<cdiv_h(RBL*128,256),256,0,stream>>>(temp_in, tr_temp_b, RBL*128);
    temp_in_mfma<<<dim3(56,4),256,0,stream>>>(AT, WtT, temp_in);
    k_f2b<<<cdiv_h(RBL*128,256),256,0,stream>>>(temp_in, tempB, RBL*128);

    // ---------------- temporal GAT ----------------
    mgemm_rt<2,4,0,false,false><<<dim3(2,3),256,0,stream>>>(tempB, gtpWT, nullptr, nullptr,
                                                            hB, RBL, 128, 128);
    k_sc<<<cdiv_h(RBL,256),256,0,stream>>>(hB, gat_tp_as, gat_tp_ad, sc_s, sc_d, RBL);
    hipMemsetAsync(nsum, 0, (size_t)RBL*4*4, stream);
    k_attE<<<cdiv_h(B_*E_TP,256),256,0,stream>>>(sc_s, sc_d, ei_tp, E_TP, NT_, a_buf, nsum);
    k_gather<false><<<RBL/4,256,0,stream>>>(hB, a_buf, nsum, nullptr, ei_tp, off_tp, list_tp,
                                            gat_tp_b, embB, E_TP, NT_);
    mgemm_rt<2,8,0,false,false><<<dim3(8,3),256,0,stream>>>(embB, w1catT_tp, b1cat_tp, nullptr,
                                                            PQ_t, RBL, 1024, 128);
    ext2_mfma<false><<<(B_*E_TP)/256,256,0,stream>>>(PQ_t, W2T_tp, ext_tp_b2, ext_tp_w3,
                                                     ext_tp_b3, ei_tp, att, E_TP, NT_,
                                                     (B_*E_TP)/256);
    k_gather<true><<<RBL/4,256,0,stream>>>(hB, a_buf, nsum, att, ei_tp, off_tp, list_tp,
                                           gat_tp_b, toutB, E_TP, NT_);

    // ---------------- temporal back-projection + ts_temp ----------------
    mgemm_rt<2,4,0,false,false><<<dim3(883,3),256,0,stream>>>(toutB, itWT, inv_temp_b, nullptr,
                                                              tback, RBL, NDM, 128);
    mgemm<4,1,1,false,false><<<dim3(1,442),256,0,stream>>>(tback, tswT_hi, ts_b, nullptr,
                                                           ts_temp, RBN, 64, LDM);

    // ---------------- concat + residual MLP encoder (MFMA) + regression head ----------------
    k_hid<<<cdiv_h(RBN*320,256),256,0,stream>>>(ts_res, ts_temp, node_emb, tid_emb, diw_emb, hist,
                                                hid, hidB);
    for (int i = 0; i < 3; ++i) {
        mgemm_rt<2,5,0,true,false><<<dim3(4,221),256,0,stream>>>(hidB, w1T_enc + (size_t)i*320*320,
                                                                 enc_b1 + i*320, nullptr, R1b, RBN, 320, 320);
        mgemm_rt<2,5,0,false,true><<<dim3(4,221),256,0,stream>>>(R1b, w2T_enc + (size_t)i*320*320,
                                                                 enc_b2 + i*320, hid, hidB, RBN, 320, 320);
    }
    mgemm<1,0,2,false,false><<<dim3(1,442),256,0,stream>>>(hidB, reg_wT, reg_b, nullptr,
                                                           out, RBN, 16, 320);
}